// Round 3
// baseline (148.458 us; speedup 1.0000x reference)
//
#include <hip/hip_runtime.h>
#include <math.h>

// Problem constants (from reference): B=32768, S=16, D=64
#define Bn 32768
#define Sn 16
#define Dn 64
#define NB 2            // batches per tile (per block iteration)
#define STRIDE 68       // padded LDS row stride in floats
#define THREADS 128     // 64 threads per batch, 2x2 output tile per thread
#define TPB 4           // tiles per block (persistent loop, pipelined)

__global__ __launch_bounds__(THREADS, 4)
void get_logit_mc_kernel(const float* __restrict__ z1,
                         const float* __restrict__ z2,
                         const float* __restrict__ pa,
                         const float* __restrict__ pb,
                         float* __restrict__ out) {
    __shared__ float zs[2][NB][Sn][STRIDE];   // 17408 B single-buffered

    const int t   = threadIdx.x;
    const int bb0 = blockIdx.x * (NB * TPB);  // first batch of this block

    const float av = pa[0];
    const float bv = pb[0];

    // compute-phase mapping: wave handles one batch; 2x2 tile per thread
    const int bl = t >> 6;                    // 0..1 batch within tile
    const int r  = (t >> 3) & 7;              // row group
    const int c  = t & 7;                     // col group

    float4 regs[8];                           // reg-staged next tile

    // ---- prologue: load tile 0 into regs (coalesced float4) ----
    #pragma unroll
    for (int k = 0; k < 8; ++k) {
        int Q     = t + k * THREADS;          // 0..1023
        int batch = Q >> 9;
        int arr   = (Q >> 8) & 1;
        int row   = (Q >> 4) & 15;
        int q     = Q & 15;
        const float* src = (arr ? z2 : z1) +
            (((size_t)(bb0 + batch) * Sn + row) * Dn + q * 4);
        regs[k] = *reinterpret_cast<const float4*>(src);
    }

    for (int tt = 0; tt < TPB; ++tt) {
        // ---- commit staged regs to LDS ----
        #pragma unroll
        for (int k = 0; k < 8; ++k) {
            int Q     = t + k * THREADS;
            int batch = Q >> 9;
            int arr   = (Q >> 8) & 1;
            int row   = (Q >> 4) & 15;
            int q     = Q & 15;
            *reinterpret_cast<float4*>(&zs[arr][batch][row][q * 4]) = regs[k];
        }
        __syncthreads();

        // ---- issue next tile's global loads (overlap with compute below) ----
        if (tt + 1 < TPB) {
            const int bbn = bb0 + (tt + 1) * NB;
            #pragma unroll
            for (int k = 0; k < 8; ++k) {
                int Q     = t + k * THREADS;
                int batch = Q >> 9;
                int arr   = (Q >> 8) & 1;
                int row   = (Q >> 4) & 15;
                int q     = Q & 15;
                const float* src = (arr ? z2 : z1) +
                    (((size_t)(bbn + batch) * Sn + row) * Dn + q * 4);
                regs[k] = *reinterpret_cast<const float4*>(src);
            }
        }

        // ---- compute current tile from LDS ----
        float acc[2][2] = {{0.f,0.f},{0.f,0.f}};
        #pragma unroll
        for (int q = 0; q < 16; ++q) {
            float4 x0 = *reinterpret_cast<const float4*>(&zs[0][bl][2*r    ][q*4]);
            float4 x1 = *reinterpret_cast<const float4*>(&zs[0][bl][2*r + 1][q*4]);
            #pragma unroll
            for (int jj = 0; jj < 2; ++jj) {
                float4 y = *reinterpret_cast<const float4*>(&zs[1][bl][2*c + jj][q*4]);
                float d;
                d = x0.x - y.x; acc[0][jj] = fmaf(d, d, acc[0][jj]);
                d = x0.y - y.y; acc[0][jj] = fmaf(d, d, acc[0][jj]);
                d = x0.z - y.z; acc[0][jj] = fmaf(d, d, acc[0][jj]);
                d = x0.w - y.w; acc[0][jj] = fmaf(d, d, acc[0][jj]);
                d = x1.x - y.x; acc[1][jj] = fmaf(d, d, acc[1][jj]);
                d = x1.y - y.y; acc[1][jj] = fmaf(d, d, acc[1][jj]);
                d = x1.z - y.z; acc[1][jj] = fmaf(d, d, acc[1][jj]);
                d = x1.w - y.w; acc[1][jj] = fmaf(d, d, acc[1][jj]);
            }
        }

        // ---- epilogue: dist -> sigmoid -> clip -> coalesced float2 stores ----
        const int gb = bb0 + tt * NB + bl;    // global batch
        #pragma unroll
        for (int ii = 0; ii < 2; ++ii) {
            float2 o;
            #pragma unroll
            for (int jj = 0; jj < 2; ++jj) {
                float dist = sqrtf(acc[ii][jj]);
                float x    = fmaf(dist, av, bv);
                float e    = __expf(-x);
                float sg   = 1.0f / (1.0f + e);
                sg = fminf(sg, 1.0f);
                sg = fmaxf(sg, 1e-8f);
                (&o.x)[jj] = sg;
            }
            int i = 2*r + ii;
            float* dst = out + ((size_t)gb * (Sn * Sn) + i * Sn + c * 2);
            *reinterpret_cast<float2*>(dst) = o;
        }

        __syncthreads();   // LDS safe to overwrite next iteration
    }
}

extern "C" void kernel_launch(void* const* d_in, const int* in_sizes, int n_in,
                              void* d_out, int out_size, void* d_ws, size_t ws_size,
                              hipStream_t stream) {
    const float* z1 = (const float*)d_in[0];
    const float* z2 = (const float*)d_in[1];
    const float* pa = (const float*)d_in[2];
    const float* pb = (const float*)d_in[3];
    float* out      = (float*)d_out;

    dim3 grid(Bn / (NB * TPB));   // 4096 blocks
    dim3 block(THREADS);
    hipLaunchKernelGGL(get_logit_mc_kernel, grid, block, 0, stream,
                       z1, z2, pa, pb, out);
}

// Round 5
// 57.216 us; speedup vs baseline: 2.5947x; 2.5947x over previous
//
#include <hip/hip_runtime.h>
#include <hip/hip_bf16.h>
#include <math.h>

// Problem constants (from reference): B=32768, S=16, D=64
#define Bn 32768
#define Sn 16
#define Dn 64
#define NB 2            // batches staged per block
#define SSTR 72         // padded LDS row stride in bf16 elements (144 B, 16B-aligned)
#define THREADS 128     // 64 threads per batch, each computes a 2x2 output tile

typedef __attribute__((ext_vector_type(8))) unsigned short ushort8v;
typedef __attribute__((ext_vector_type(4))) unsigned short ushort4v;

static __device__ inline unsigned short f2bf(float f) {
    __hip_bfloat16 h = __float2bfloat16(f);            // RN conversion
    return *reinterpret_cast<unsigned short*>(&h);
}
static __device__ inline float bf2f(unsigned short u) { // exact (shift)
    union { unsigned int i; float f; } v;
    v.i = ((unsigned int)u) << 16;
    return v.f;
}

__global__ __launch_bounds__(THREADS, 8)
void get_logit_mc_kernel(const float* __restrict__ z1,
                         const float* __restrict__ z2,
                         const float* __restrict__ pa,
                         const float* __restrict__ pb,
                         float* __restrict__ out) {
    // bf16 tiles: 2 arrays x NB batches x 16 rows x 72 shorts = 9216 B
    __shared__ __align__(16) unsigned short zs[2][NB][Sn][SSTR];

    const int t  = threadIdx.x;
    const int bb = blockIdx.x * NB;

    // ---- stage: load f32 coalesced, convert to bf16, write 8B to LDS ----
    #pragma unroll
    for (int k = 0; k < 8; ++k) {
        int Q     = t + k * THREADS;          // 0..1023 quads
        int batch = Q >> 9;
        int arr   = (Q >> 8) & 1;
        int row   = (Q >> 4) & 15;
        int q     = Q & 15;                   // d-quad 0..15
        const float* src = (arr ? z2 : z1) +
            (((size_t)(bb + batch) * Sn + row) * Dn + q * 4);
        float4 v = *reinterpret_cast<const float4*>(src);
        ushort4v w;
        w.x = f2bf(v.x); w.y = f2bf(v.y); w.z = f2bf(v.z); w.w = f2bf(v.w);
        *reinterpret_cast<ushort4v*>(&zs[arr][batch][row][q * 4]) = w;
    }

    const float av = pa[0];
    const float bv = pb[0];

    __syncthreads();

    // ---- compute: thread = batch_local*64 + r*8 + c; 2x2 tile ----
    const int bl = t >> 6;                    // wave = batch
    const int r  = (t >> 3) & 7;
    const int c  = t & 7;

    float acc[2][2] = {{0.f,0.f},{0.f,0.f}};

    #pragma unroll
    for (int qq = 0; qq < 8; ++qq) {          // 8 chunks of 8 elements
        ushort8v x0 = *reinterpret_cast<const ushort8v*>(&zs[0][bl][2*r    ][qq*8]);
        ushort8v x1 = *reinterpret_cast<const ushort8v*>(&zs[0][bl][2*r + 1][qq*8]);
        ushort8v y0 = *reinterpret_cast<const ushort8v*>(&zs[1][bl][2*c    ][qq*8]);
        ushort8v y1 = *reinterpret_cast<const ushort8v*>(&zs[1][bl][2*c + 1][qq*8]);
        #pragma unroll
        for (int e = 0; e < 8; ++e) {
            float a0 = bf2f(x0[e]);
            float a1 = bf2f(x1[e]);
            float b0 = bf2f(y0[e]);
            float b1 = bf2f(y1[e]);
            float d;
            d = a0 - b0; acc[0][0] = fmaf(d, d, acc[0][0]);
            d = a0 - b1; acc[0][1] = fmaf(d, d, acc[0][1]);
            d = a1 - b0; acc[1][0] = fmaf(d, d, acc[1][0]);
            d = a1 - b1; acc[1][1] = fmaf(d, d, acc[1][1]);
        }
    }

    // ---- epilogue: dist -> sigmoid -> clip -> coalesced float2 stores ----
    #pragma unroll
    for (int ii = 0; ii < 2; ++ii) {
        float2 o;
        #pragma unroll
        for (int jj = 0; jj < 2; ++jj) {
            float dist = sqrtf(acc[ii][jj]);
            float x    = fmaf(dist, av, bv);
            float e    = __expf(-x);
            float sg   = 1.0f / (1.0f + e);
            sg = fminf(sg, 1.0f);
            sg = fmaxf(sg, 1e-8f);
            (&o.x)[jj] = sg;
        }
        int i = 2*r + ii;
        float* dst = out + ((size_t)(bb + bl) * (Sn * Sn) + i * Sn + c * 2);
        *reinterpret_cast<float2*>(dst) = o;
    }
}

extern "C" void kernel_launch(void* const* d_in, const int* in_sizes, int n_in,
                              void* d_out, int out_size, void* d_ws, size_t ws_size,
                              hipStream_t stream) {
    const float* z1 = (const float*)d_in[0];
    const float* z2 = (const float*)d_in[1];
    const float* pa = (const float*)d_in[2];
    const float* pb = (const float*)d_in[3];
    float* out      = (float*)d_out;

    dim3 grid(Bn / NB);   // 16384 blocks
    dim3 block(THREADS);
    hipLaunchKernelGGL(get_logit_mc_kernel, grid, block, 0, stream,
                       z1, z2, pa, pb, out);
}

// Round 6
// 49.835 us; speedup vs baseline: 2.9790x; 1.1481x over previous
//
#include <hip/hip_runtime.h>
#include <hip/hip_bf16.h>
#include <math.h>

// Problem constants: B=32768, S=16, D=64
#define Bn 32768
#define Sn 16
#define Dn 64
#define THREADS 256
#define WPB 4            // waves per block; one batch per wave

typedef __attribute__((ext_vector_type(8))) short bf16x8;   // 8 bf16 (4 VGPRs)
typedef __attribute__((ext_vector_type(4))) float f32x4;

static __device__ inline unsigned short f2bf(float f) {
    __hip_bfloat16 h = __float2bfloat16(f);                 // RN
    return *reinterpret_cast<unsigned short*>(&h);
}
static __device__ inline float bf2f(unsigned short u) {     // exact
    union { unsigned int i; float f; } v;
    v.i = ((unsigned int)u) << 16;
    return v.f;
}

// convert 8 consecutive f32 -> bf16x8 fragment, accumulating sum of squares
// of the ROUNDED values into s (so d2 = ||x~||^2+||y~||^2-2<x~,y~> >= 0).
static __device__ inline bf16x8 cvt_frag(float4 lo, float4 hi, float& s) {
    bf16x8 r;
    const float* pl = &lo.x;
    const float* ph = &hi.x;
    #pragma unroll
    for (int j = 0; j < 4; ++j) {
        unsigned short u = f2bf(pl[j]);
        float f = bf2f(u);
        s = fmaf(f, f, s);
        r[j] = (short)u;
    }
    #pragma unroll
    for (int j = 0; j < 4; ++j) {
        unsigned short u = f2bf(ph[j]);
        float f = bf2f(u);
        s = fmaf(f, f, s);
        r[4 + j] = (short)u;
    }
    return r;
}

__global__ __launch_bounds__(THREADS, 4)
void get_logit_mc_kernel(const float* __restrict__ z1,
                         const float* __restrict__ z2,
                         const float* __restrict__ pa,
                         const float* __restrict__ pb,
                         float* __restrict__ out) {
    const int t     = threadIdx.x;
    const int wave  = t >> 6;
    const int lane  = t & 63;
    const int batch = blockIdx.x * WPB + wave;
    const int m     = lane & 15;   // A row / B col index
    const int g     = lane >> 4;   // k-group (8 k's per group per mfma)

    // Fragment loads: lane covers z[batch][m][k], k in [8g,8g+8) and [32+8g,...)
    // Union over the wave = the full contiguous 4KB tile of each input.
    const float* p1 = z1 + ((size_t)batch << 10) + (m << 6);
    const float* p2 = z2 + ((size_t)batch << 10) + (m << 6);

    float4 a0 = *reinterpret_cast<const float4*>(p1 + g * 8);
    float4 a1 = *reinterpret_cast<const float4*>(p1 + g * 8 + 4);
    float4 a2 = *reinterpret_cast<const float4*>(p1 + 32 + g * 8);
    float4 a3 = *reinterpret_cast<const float4*>(p1 + 32 + g * 8 + 4);
    float4 b0 = *reinterpret_cast<const float4*>(p2 + g * 8);
    float4 b1 = *reinterpret_cast<const float4*>(p2 + g * 8 + 4);
    float4 b2 = *reinterpret_cast<const float4*>(p2 + 32 + g * 8);
    float4 b3 = *reinterpret_cast<const float4*>(p2 + 32 + g * 8 + 4);

    float s1 = 0.0f, s2 = 0.0f;
    bf16x8 fa0 = cvt_frag(a0, a1, s1);
    bf16x8 fa1 = cvt_frag(a2, a3, s1);
    bf16x8 fb0 = cvt_frag(b0, b1, s2);
    bf16x8 fb1 = cvt_frag(b2, b3, s2);

    // dots[m][n] = z1[m] . z2[n]  via 2 K-steps of 16x16x32 bf16 MFMA
    f32x4 acc = {0.f, 0.f, 0.f, 0.f};
    acc = __builtin_amdgcn_mfma_f32_16x16x32_bf16(fa0, fb0, acc, 0, 0, 0);
    acc = __builtin_amdgcn_mfma_f32_16x16x32_bf16(fa1, fb1, acc, 0, 0, 0);

    // Row-norm reduce: lanes {m, m+16, m+32, m+48} hold disjoint k-ranges.
    s1 += __shfl_xor(s1, 16);
    s1 += __shfl_xor(s1, 32);
    s2 += __shfl_xor(s2, 16);
    s2 += __shfl_xor(s2, 32);
    // now: s1 = ||z1~[m]||^2 in every lane with (lane&15)==m; same for s2.

    const float av = pa[0];
    const float bv = pb[0];

    // C/D layout (m89): acc[j] at lane l -> row=(l>>4)*4+j, col=l&15
    float* po = out + ((size_t)batch << 8);
    #pragma unroll
    for (int j = 0; j < 4; ++j) {
        int   row = g * 4 + j;
        float s1r = __shfl(s1, row);            // ||z1~[row]||^2 from lane 'row'
        float d2  = s1r + s2 - 2.0f * acc[j];
        d2 = fmaxf(d2, 0.0f);
        float dist = sqrtf(d2);
        float x    = fmaf(dist, av, bv);
        float e    = __expf(-x);
        float sg   = 1.0f / (1.0f + e);
        sg = fminf(sg, 1.0f);
        sg = fmaxf(sg, 1e-8f);
        po[row * 16 + m] = sg;                  // 16-lane groups = 64B segments
    }
}

extern "C" void kernel_launch(void* const* d_in, const int* in_sizes, int n_in,
                              void* d_out, int out_size, void* d_ws, size_t ws_size,
                              hipStream_t stream) {
    const float* z1 = (const float*)d_in[0];
    const float* z2 = (const float*)d_in[1];
    const float* pa = (const float*)d_in[2];
    const float* pb = (const float*)d_in[3];
    float* out      = (float*)d_out;

    dim3 grid(Bn / WPB);     // 8192 blocks
    dim3 block(THREADS);
    hipLaunchKernelGGL(get_logit_mc_kernel, grid, block, 0, stream,
                       z1, z2, pa, pb, out);
}